// Round 14
// baseline (126.909 us; speedup 1.0000x reference)
//
#include <hip/hip_runtime.h>

// ---------------------------------------------------------------------------
// KP_Decoder: hypernet -> (k,v,q) -> attention -> top2 MoE -> combine softmax
// B=32 G=512 N=512 EMB=128 H=8 DK=16 E=8 FH=512 K=2
// R3-R13: bf16 MFMA everywhere; fused fixed-max softmaxes; q-split attn;
//         mask-flag skip; split prep; V pre-transposed; bf16 AO/Y; mh fused.
// R14: k_gemm2f fast exp-based tanh (libm tanhf -> 2 TRANS + 5 VALU);
//      k_moe 128-token tiles @512 thr (halved weight staging, 2 waves/SIMD).
// ---------------------------------------------------------------------------

typedef __attribute__((ext_vector_type(8))) __bf16 bf16x8;
typedef __attribute__((ext_vector_type(4))) float f32x4;

// ws layout (float offsets)
static constexpr long OFF_MID   = 0;        // 8
static constexpr long OFF_PREFL = 8;        // 8
static constexpr long OFF_WL    = 16;       // 128 (Wq[:,128] capacity col)
static constexpr long OFF_WKB   = 256;      // 128x128 bf16
static constexpr long OFF_WVB   = 8448;     // 128x128 bf16
static constexpr long OFF_WCB   = 16640;    // 128x128 bf16
static constexpr long OFF_QB    = 24832;    // 32x128 qbase fp32
static constexpr long OFF_MFLAG = 28928;    // 16384 bytes (4096 floats)
static constexpr long OFF_CNT   = 33024;    // 8 ints
static constexpr long OFF_TOK   = 33032;    // 8*16384 ints
static constexpr long OFF_WGT   = 164104;   // 8*16384 floats
static constexpr long OFF_AO    = 295176;   // 16384x128 bf16 AO (1,048,576 f)
static constexpr long OFF_Y0    = 1343752;  // 16384x128 bf16 Y0
static constexpr long OFF_Y1    = 2392328;  // 16384x128 bf16 Y1
static constexpr long OFF_ENCB  = 3440904;  // 16384x128 bf16 enc
// total 4,489,480 floats = 17.96 MB

__device__ __forceinline__ unsigned f2bf(float x) {
  union { float f; unsigned u; } v; v.f = x;
  return ((v.u + 0x7FFFu + ((v.u >> 16) & 1u)) >> 16) & 0xFFFFu;
}
__device__ __forceinline__ float bflo(unsigned u) {
  union { unsigned u; float f; } v; v.u = u << 16; return v.f;
}
__device__ __forceinline__ float bfhi(unsigned u) {
  union { unsigned u; float f; } v; v.u = u & 0xFFFF0000u; return v.f;
}

// ---------------- k_prep1: hypernet (1 block) + cvt + mask flags -----------
__global__ __launch_bounds__(256)
void k_prep1(const float* __restrict__ pref, const float* __restrict__ fc1w,
             const float* __restrict__ fc1b, const float* __restrict__ fc2w,
             const float* __restrict__ fc2b, const float* __restrict__ fc3w,
             const float* __restrict__ fc3b, const float* __restrict__ gpw,
             const float* __restrict__ hWq, const float* __restrict__ mask,
             const float* __restrict__ ew1, const float* __restrict__ ew2,
             const float* __restrict__ enc,
             unsigned short* __restrict__ w1b, unsigned short* __restrict__ w2b,
             unsigned short* __restrict__ encb, float* __restrict__ ws) {
  const int bid = blockIdx.x;
  const int tid = threadIdx.x;
  if (bid == 0) {
    __shared__ float h1[256];
    __shared__ float h2[256];
    __shared__ float mid[8];
    const float p0 = pref[0], p1 = pref[1];
    h1[tid] = fc1w[2*tid]*p0 + fc1w[2*tid+1]*p1 + fc1b[tid];
    __syncthreads();
    float s = 0.f;
    for (int j = 0; j < 256; ++j) s = fmaf(fc2w[tid*256+j], h1[j], s);
    h2[tid] = s + fc2b[tid];
    __syncthreads();
    if (tid < 8) {
      float s2 = 0.f;
      for (int j = 0; j < 256; ++j) s2 = fmaf(fc3w[tid*256+j], h2[j], s2);
      mid[tid] = s2 + fc3b[tid];
    }
    __syncthreads();
    if (tid < 8) {
      ws[OFF_MID + tid] = mid[tid];
      float s3 = 0.f;
      for (int i = 0; i < 8; ++i) s3 = fmaf(mid[i], gpw[i*8 + tid], s3);
      ws[OFF_PREFL + tid] = s3;
      ((int*)(ws + OFF_CNT))[tid] = 0;
    }
    if (tid >= 16 && tid < 144) {
      const int o = tid - 16;
      ws[OFF_WL + o] = hWq[((long)o*129 + 128)*2]*mid[0]
                     + hWq[((long)o*129 + 128)*2 + 1]*mid[1];
    }
    return;
  }
  if (bid <= 3072) {
    const int i = (bid-1)*256 + tid;
    const float* src;
    unsigned short* dst;
    if (i < 131072)      { src = ew1 + (long)i*4;          dst = w1b + (long)i*4; }
    else if (i < 262144) { src = ew2 + (long)(i-131072)*4; dst = w2b + (long)(i-131072)*4; }
    else                 { src = enc + (long)(i-262144)*4; dst = encb + (long)(i-262144)*4; }
    const float4 v = *(const float4*)src;
    uint2 p;
    p.x = f2bf(v.x) | (f2bf(v.y) << 16);
    p.y = f2bf(v.z) | (f2bf(v.w) << 16);
    *(uint2*)dst = p;
    return;
  }
  // mask flags: 8 rows per block
  __shared__ int fl[8];
  const int rowbase = (bid - 3073) * 8;
  const int r = tid >> 5, seg = tid & 31;
  if (tid < 8) fl[tid] = 0;
  __syncthreads();
  const float* mrow = mask + (long)(rowbase + r)*512 + seg*16;
  int nz = 0;
#pragma unroll
  for (int c = 0; c < 4; ++c) {
    const float4 v = *(const float4*)(mrow + c*4);
    nz |= (v.x != 0.f) | (v.y != 0.f) | (v.z != 0.f) | (v.w != 0.f);
  }
  if (nz) atomicOr(&fl[r], 1);
  __syncthreads();
  if (tid < 8) ((char*)(ws + OFF_MFLAG))[rowbase + tid] = (char)fl[tid];
}

// ---------------- k_prep2: Wk/Wv/Wc heads + qbase (reads mid from ws) ------
__global__ __launch_bounds__(256)
void k_prep2(const float* __restrict__ graph,
             const float* __restrict__ hWq, const float* __restrict__ hWk,
             const float* __restrict__ hWv, const float* __restrict__ hWc,
             float* __restrict__ ws) {
  const int bid = blockIdx.x;
  const int tid = threadIdx.x;
  __shared__ float mid[8];
  __shared__ float g[2][128];
  if (tid < 8) mid[tid] = ws[OFF_MID + tid];
  __syncthreads();
  if (bid < 192) {
    const int i = bid*256 + tid;   // 0..49151
    if (i < 16384) {
      ((unsigned short*)(ws + OFF_WKB))[i] =
          (unsigned short)f2bf(hWk[2*i]*mid[2] + hWk[2*i+1]*mid[3]);
    } else if (i < 32768) {
      const int j = i - 16384;
      ((unsigned short*)(ws + OFF_WVB))[j] =
          (unsigned short)f2bf(hWv[2*j]*mid[4] + hWv[2*j+1]*mid[5]);
    } else {
      const int j = i - 32768;
      ((unsigned short*)(ws + OFF_WCB))[j] =
          (unsigned short)f2bf(hWc[2*j]*mid[6] + hWc[2*j+1]*mid[7]);
    }
    return;
  }
  const int qb = bid - 192;
  const int b0 = qb*2;
  {
    const int bb = tid >> 7, ii = tid & 127;
    g[bb][ii] = graph[(b0+bb)*128 + ii];
  }
  __syncthreads();
  const float m0 = mid[0], m1 = mid[1];
  const int bb = tid >> 7, o = tid & 127;
  const float* hq = hWq + (long)o*129*2;
  float acc = 0.f;
  for (int i2 = 0; i2 < 128; ++i2) {
    const float w = hq[2*i2]*m0 + hq[2*i2+1]*m1;
    acc = fmaf(g[bb][i2], w, acc);
  }
  ws[OFF_QB + (b0+bb)*128 + o] = acc;
}

// ---------------- shared swizzled-LDS fragment loader (256B rows) ----------
__device__ __forceinline__ bf16x8 ld_frag(const unsigned short* base, int row, int bytecol) {
  const int addr = row*256 + (bytecol ^ ((row & 7) << 4));
  return *(const bf16x8*)((const char*)base + addr);
}

// ---------------- k_kv: bf16 MFMA GEMM, K row-major, V TRANSPOSED ----------
__global__ __launch_bounds__(256)
void k_kv(const unsigned short* __restrict__ encb,
          const unsigned short* __restrict__ wkb,
          const unsigned short* __restrict__ wvb,
          unsigned short* __restrict__ Kb, unsigned short* __restrict__ Vtg) {
  __shared__ unsigned short Ws[128*128];
  __shared__ unsigned short Xs[64*128];
  const int tid = threadIdx.x;
  const int nbase = blockIdx.x * 64;
  const unsigned short* Wb = blockIdx.y ? wvb : wkb;
#pragma unroll
  for (int s = 0; s < 8; ++s) {
    const int id = tid + s*256;
    const int fr = id >> 4, c16 = id & 15;
    const uint4 v = *(const uint4*)(Wb + (long)fr*128 + c16*8);
    *(uint4*)((char*)Ws + fr*256 + ((c16*16) ^ ((fr & 7) << 4))) = v;
  }
#pragma unroll
  for (int s = 0; s < 4; ++s) {
    const int id = tid + s*256;
    const int r = id >> 4, c16 = id & 15;
    const uint4 v = *(const uint4*)(encb + (long)(nbase + r)*128 + c16*8);
    *(uint4*)((char*)Xs + r*256 + ((c16*16) ^ ((r & 7) << 4))) = v;
  }
  __syncthreads();
  const int w = tid >> 6, l = tid & 63, lq = l >> 4, lr = l & 15;
  f32x4 acc[2][4];
#pragma unroll
  for (int a = 0; a < 2; ++a)
#pragma unroll
    for (int m = 0; m < 4; ++m) acc[a][m] = (f32x4){0.f, 0.f, 0.f, 0.f};
#pragma unroll
  for (int ks = 0; ks < 4; ++ks) {
    const int bcol = ks*64 + lq*16;
    const bf16x8 a0 = ld_frag(Ws, (2*w  )*16 + lr, bcol);
    const bf16x8 a1 = ld_frag(Ws, (2*w+1)*16 + lr, bcol);
    const bf16x8 b0 = ld_frag(Xs, 0*16 + lr, bcol);
    const bf16x8 b1 = ld_frag(Xs, 1*16 + lr, bcol);
    const bf16x8 b2 = ld_frag(Xs, 2*16 + lr, bcol);
    const bf16x8 b3 = ld_frag(Xs, 3*16 + lr, bcol);
    acc[0][0] = __builtin_amdgcn_mfma_f32_16x16x32_bf16(a0, b0, acc[0][0], 0, 0, 0);
    acc[0][1] = __builtin_amdgcn_mfma_f32_16x16x32_bf16(a0, b1, acc[0][1], 0, 0, 0);
    acc[0][2] = __builtin_amdgcn_mfma_f32_16x16x32_bf16(a0, b2, acc[0][2], 0, 0, 0);
    acc[0][3] = __builtin_amdgcn_mfma_f32_16x16x32_bf16(a0, b3, acc[0][3], 0, 0, 0);
    acc[1][0] = __builtin_amdgcn_mfma_f32_16x16x32_bf16(a1, b0, acc[1][0], 0, 0, 0);
    acc[1][1] = __builtin_amdgcn_mfma_f32_16x16x32_bf16(a1, b1, acc[1][1], 0, 0, 0);
    acc[1][2] = __builtin_amdgcn_mfma_f32_16x16x32_bf16(a1, b2, acc[1][2], 0, 0, 0);
    acc[1][3] = __builtin_amdgcn_mfma_f32_16x16x32_bf16(a1, b3, acc[1][3], 0, 0, 0);
  }
  if (blockIdx.y == 0) {
#pragma unroll
    for (int obi = 0; obi < 2; ++obi) {
      const int o0 = (2*w + obi)*16 + lq*4;
#pragma unroll
      for (int mb = 0; mb < 4; ++mb) {
        const long n = nbase + mb*16 + lr;
        uint2 pp;
        pp.x = f2bf(acc[obi][mb][0]) | (f2bf(acc[obi][mb][1]) << 16);
        pp.y = f2bf(acc[obi][mb][2]) | (f2bf(acc[obi][mb][3]) << 16);
        *(uint2*)(Kb + n*128 + o0) = pp;
      }
    }
  } else {
    const int b = nbase >> 9;
    const int nn0 = nbase & 511;
#pragma unroll
    for (int obi = 0; obi < 2; ++obi) {
      const int o0 = (2*w + obi)*16 + lq*4;
#pragma unroll
      for (int mb = 0; mb < 4; ++mb) {
        const int nn = nn0 + mb*16 + lr;
#pragma unroll
        for (int j = 0; j < 4; ++j) {
          const int o = o0 + j;
          Vtg[(((long)b*8 + (o >> 4))*16 + (o & 15))*512 + nn] =
              (unsigned short)f2bf(acc[obi][mb][j]);
        }
      }
    }
  }
}

// ---------------- MFMA flash attention v7: dual PV accumulators ------------
__global__ __launch_bounds__(512, 8)
void k_attn(const unsigned short* __restrict__ Kb,
            const unsigned short* __restrict__ Vtg,
            const float* __restrict__ ws, const float* __restrict__ cap,
            const float* __restrict__ mask, unsigned short* __restrict__ AOb) {
  const int bid = blockIdx.x;
  const int b = bid & 31, h = (bid >> 5) & 7, qh = bid >> 8;
  __shared__ unsigned short Kbf[512*24];  // 24 KB
  __shared__ unsigned short Vt[16*536];   // 16.75 KB
  __shared__ unsigned short Ps[8*16*40];  // 10 KB
  const int tid = threadIdx.x;
#pragma unroll
  for (int it = 0; it < 2; ++it) {
    const int i = tid + it*512;           // 0..1023
    const int n = i >> 1, hf = i & 1;
    const uint4 kv = *(const uint4*)(Kb + (long)(b*512 + n)*128 + h*16 + hf*8);
    *(uint4*)(Kbf + n*24 + hf*8) = kv;
    const int d = i >> 6, c = i & 63;
    const uint4 vv = *(const uint4*)(Vtg + ((long)(b*8 + h)*16 + d)*512 + c*8);
    *(uint4*)(Vt + d*536 + c*8) = vv;
  }
  const int w = tid >> 6, l = tid & 63;
  const int lq = l >> 4, lr = l & 15;
  const int grow = qh*128 + w*16 + lr;
  bf16x8 qf;
  {
    union { uint4 u; bf16x8 v; } cv;
    cv.u = make_uint4(0u, 0u, 0u, 0u);
    if (lq < 2) {
      const float* qbp = ws + OFF_QB + b*128 + h*16 + lq*8;
      const float* wlp = ws + OFF_WL + h*16 + lq*8;
      const float cp = cap[b*512 + grow];
      float qv[8];
#pragma unroll
      for (int j = 0; j < 8; ++j) qv[j] = (qbp[j] + cp*wlp[j]) * 0.25f;
      cv.u.x = f2bf(qv[0]) | (f2bf(qv[1]) << 16);
      cv.u.y = f2bf(qv[2]) | (f2bf(qv[3]) << 16);
      cv.u.z = f2bf(qv[4]) | (f2bf(qv[5]) << 16);
      cv.u.w = f2bf(qv[6]) | (f2bf(qv[7]) << 16);
    }
    qf = cv.v;
  }
  const int mf = ((const char*)(ws + OFF_MFLAG))[b*512 + grow];
  const bool usemask = __any(mf != 0);
  unsigned short* Pw = Ps + w*16*40;
  const int psw = (lr & 3) << 3;
  __syncthreads();
  float lsum = 0.f;
  f32x4 oaccA = {0.f, 0.f, 0.f, 0.f};
  f32x4 oaccB = {0.f, 0.f, 0.f, 0.f};
  const float* mrow = mask + ((long)(b*512 + grow))*512 + lq*4;
#pragma unroll 2
  for (int qc = 0; qc < 16; ++qc) {       // 16 chunks of 32 n, independent
    const int n0 = qc*32;
    f32x4 s[2];
#pragma unroll
    for (int nb = 0; nb < 2; ++nb) {
      bf16x8 kf;
      {
        union { uint4 u; bf16x8 v; } cv;
        cv.u = make_uint4(0u, 0u, 0u, 0u);
        if (lq < 2) cv.u = *(const uint4*)(Kbf + (n0 + nb*16 + lr)*24 + lq*8);
        kf = cv.v;
      }
      s[nb] = __builtin_amdgcn_mfma_f32_16x16x32_bf16(
          kf, qf, (f32x4){0.f, 0.f, 0.f, 0.f}, 0, 0, 0);
      if (usemask) {
        const float4 mk = *(const float4*)(mrow + n0 + nb*16);
        s[nb][0] += mk.x; s[nb][1] += mk.y; s[nb][2] += mk.z; s[nb][3] += mk.w;
      }
    }
#pragma unroll
    for (int nb = 0; nb < 2; ++nb) {
      const float e0 = __expf(s[nb][0]);
      const float e1 = __expf(s[nb][1]);
      const float e2 = __expf(s[nb][2]);
      const float e3 = __expf(s[nb][3]);
      lsum += (e0 + e1) + (e2 + e3);
      uint2 pp;
      asm("v_cvt_pk_bf16_f32 %0, %1, %2" : "=v"(pp.x) : "v"(e0), "v"(e1));
      asm("v_cvt_pk_bf16_f32 %0, %1, %2" : "=v"(pp.y) : "v"(e2), "v"(e3));
      *(uint2*)(Pw + lr*40 + ((nb*16 + lq*4) ^ psw)) = pp;
    }
    const bf16x8 va = *(const bf16x8*)(Vt + lr*536 + n0 + lq*8);
    const bf16x8 pb = *(const bf16x8*)(Pw + lr*40 + (lq*8 ^ psw));
    if (qc & 1) oaccB = __builtin_amdgcn_mfma_f32_16x16x32_bf16(va, pb, oaccB, 0, 0, 0);
    else        oaccA = __builtin_amdgcn_mfma_f32_16x16x32_bf16(va, pb, oaccA, 0, 0, 0);
  }
  lsum += __shfl_xor(lsum, 16);
  lsum += __shfl_xor(lsum, 32);
  const float inv = 1.f / lsum;
  uint2 op;
  op.x = f2bf((oaccA[0]+oaccB[0])*inv) | (f2bf((oaccA[1]+oaccB[1])*inv) << 16);
  op.y = f2bf((oaccA[2]+oaccB[2])*inv) | (f2bf((oaccA[3]+oaccB[3])*inv) << 16);
  *(uint2*)(AOb + (long)(b*512 + grow)*128 + h*16 + lq*4) = op;
}

// ---------------- gating: top-2 + expert lists (bf16 AO) -------------------
__global__ __launch_bounds__(256)
void k_gate(const unsigned short* __restrict__ AOb, const float* __restrict__ gw,
            float* __restrict__ ws) {
  const int tid = threadIdx.x;
  const int t = blockIdx.x*256 + tid;
  const unsigned short* x = AOb + (long)t*128;
  float lg[8];
  {
    const float* pl = ws + OFF_PREFL;
#pragma unroll
    for (int e = 0; e < 8; ++e) lg[e] = pl[e];
  }
  for (int i = 0; i < 128; i += 8) {
    const uint4 xv = *(const uint4*)(x + i);
    float xf[8];
    xf[0] = bflo(xv.x); xf[1] = bfhi(xv.x);
    xf[2] = bflo(xv.y); xf[3] = bfhi(xv.y);
    xf[4] = bflo(xv.z); xf[5] = bfhi(xv.z);
    xf[6] = bflo(xv.w); xf[7] = bfhi(xv.w);
#pragma unroll
    for (int u = 0; u < 8; ++u) {
      const float xi = xf[u];
      const float4 ga = *(const float4*)(gw + (i+u)*8);
      const float4 gb = *(const float4*)(gw + (i+u)*8 + 4);
      lg[0] = fmaf(xi, ga.x, lg[0]); lg[1] = fmaf(xi, ga.y, lg[1]);
      lg[2] = fmaf(xi, ga.z, lg[2]); lg[3] = fmaf(xi, ga.w, lg[3]);
      lg[4] = fmaf(xi, gb.x, lg[4]); lg[5] = fmaf(xi, gb.y, lg[5]);
      lg[6] = fmaf(xi, gb.z, lg[6]); lg[7] = fmaf(xi, gb.w, lg[7]);
    }
  }
  int i0 = 0; float v0 = lg[0];
#pragma unroll
  for (int e = 1; e < 8; ++e) if (lg[e] > v0) { v0 = lg[e]; i0 = e; }
  int i1 = -1; float v1 = -1e30f;
#pragma unroll
  for (int e = 0; e < 8; ++e) if (e != i0 && lg[e] > v1) { v1 = lg[e]; i1 = e; }
  const float e1 = __expf(v1 - v0);
  const float w0 = 1.f / (1.f + e1);
  const float w1 = 1.f - w0;
  __shared__ int bcnt[8];
  __shared__ int gbase[8];
  if (tid < 8) bcnt[tid] = 0;
  __syncthreads();
  const int p0 = atomicAdd(&bcnt[i0], 1);
  const int p1 = atomicAdd(&bcnt[i1], 1);
  __syncthreads();
  if (tid < 8) {
    int* cnt = (int*)(ws + OFF_CNT);
    gbase[tid] = (bcnt[tid] > 0) ? atomicAdd(&cnt[tid], bcnt[tid]) : 0;
  }
  __syncthreads();
  int* tokp = (int*)(ws + OFF_TOK);
  float* wgtp = ws + OFF_WGT;
  const int s0 = gbase[i0] + p0;
  tokp[i0*16384 + s0] = t;             // rank 0
  wgtp[i0*16384 + s0] = w0;
  const int s1 = gbase[i1] + p1;
  tokp[i1*16384 + s1] = t | (1 << 30); // rank 1
  wgtp[i1*16384 + s1] = w1;
}

// ---------------- MoE experts: 128-token tiles, 512 threads ----------------
// grid (128, 8). Wave w (0..7) owns 16 f/o rows; 8 token blocks of 16.
__global__ __launch_bounds__(512)
void k_moe(const unsigned short* __restrict__ AOb,
           const unsigned short* __restrict__ w1b,
           const unsigned short* __restrict__ w2b,
           const float* __restrict__ eb1, const float* __restrict__ eb2,
           float* __restrict__ ws,
           unsigned short* __restrict__ Y0b, unsigned short* __restrict__ Y1b) {
  const int e = blockIdx.y;
  const int ce = ((const int*)(ws + OFF_CNT))[e];
  const int base = blockIdx.x * 128;
  if (base >= ce) return;
  const int nt = min(128, ce - base);

  __shared__ unsigned short Xs[128*128];   // 32 KB
  __shared__ unsigned short Wts[128*128];  // 32 KB
  __shared__ unsigned short Hs[128*128];   // 32 KB
  __shared__ float seb1[512];
  __shared__ float seb2[128];
  __shared__ int   stok[128];
  __shared__ float swgt[128];

  const int tid = threadIdx.x;
  if (tid < 128) {
    if (tid < nt) {
      stok[tid] = ((const int*)(ws + OFF_TOK))[e*16384 + base + tid];
      swgt[tid] = (ws + OFF_WGT)[e*16384 + base + tid];
    } else { stok[tid] = -1; swgt[tid] = 0.f; }
  }
  if (tid >= 128 && tid < 256) seb2[tid-128] = eb2[e*128 + tid-128];
  seb1[tid] = eb1[e*512 + tid];
  __syncthreads();

  // gather X (bf16 AO), swizzled uint4 writes
#pragma unroll
  for (int r4 = 0; r4 < 4; ++r4) {
    const int id = tid + r4*512;          // 0..2047
    const int r = id >> 4, c16 = id & 15;
    const int pk = stok[r];
    uint4 v = make_uint4(0u, 0u, 0u, 0u);
    if (pk >= 0) v = *(const uint4*)(AOb + (long)(pk & 0x3FFFFFFF)*128 + c16*8);
    *(uint4*)((char*)Xs + r*256 + ((c16*16) ^ ((r & 7) << 4))) = v;
  }

  const int w  = tid >> 6;   // 0..7
  const int l  = tid & 63;
  const int lq = l >> 4;
  const int lr = l & 15;

  f32x4 yacc[8];
#pragma unroll
  for (int m = 0; m < 8; ++m) yacc[m] = (f32x4){0.f, 0.f, 0.f, 0.f};

  for (int fc = 0; fc < 4; ++fc) {
    __syncthreads();
    {
      const long wb = (long)(e*512 + fc*128) * 128;
#pragma unroll
      for (int s = 0; s < 4; ++s) {
        const int id = tid + s*512;
        const int fr = id >> 4, c16 = id & 15;
        const uint4 v = *(const uint4*)(w1b + wb + (long)fr*128 + c16*8);
        *(uint4*)((char*)Wts + fr*256 + ((c16*16) ^ ((fr & 7) << 4))) = v;
      }
    }
    __syncthreads();
    f32x4 hacc[8];
#pragma unroll
    for (int m = 0; m < 8; ++m) hacc[m] = (f32x4){0.f, 0.f, 0.f, 0.f};
#pragma unroll
    for (int ks = 0; ks < 4; ++ks) {
      const int bcol = ks*64 + lq*16;
      const bf16x8 a0 = ld_frag(Wts, w*16 + lr, bcol);
#pragma unroll
      for (int mb = 0; mb < 8; ++mb) {
        const bf16x8 bm = ld_frag(Xs, mb*16 + lr, bcol);
        hacc[mb] = __builtin_amdgcn_mfma_f32_16x16x32_bf16(a0, bm, hacc[mb], 0, 0, 0);
      }
    }
    __syncthreads();
    {
      const int fb = w*16 + lq*4;
      const float4 bia = *(const float4*)&seb1[fc*128 + fb];
#pragma unroll
      for (int mb = 0; mb < 8; ++mb) {
        const int m = mb*16 + lr;
        const float h0 = fmaxf(hacc[mb][0] + bia.x, 0.f);
        const float h1 = fmaxf(hacc[mb][1] + bia.y, 0.f);
        const float h2 = fmaxf(hacc[mb][2] + bia.z, 0.f);
        const float h3 = fmaxf(hacc[mb][3] + bia.w, 0.f);
        uint2 p;
        p.x = f2bf(h0) | (f2bf(h1) << 16);
        p.y = f2bf(h2) | (f2bf(h3) << 16);
        const int bc = (fb*2) ^ ((m & 7) << 4);
        *(uint2*)((char*)Hs + m*256 + bc) = p;
      }
    }
    {
      const long wb = (long)(e*128) * 512 + fc*128;
#pragma unroll
      for (int s = 0; s < 4; ++s) {
        const int id = tid + s*512;
        const int orr = id >> 4, c16 = id & 15;
        const uint4 v = *(const uint4*)(w2b + wb + (long)orr*512 + c16*8);
        *(uint4*)((char*)Wts + orr*256 + ((c16*16) ^ ((orr & 7) << 4))) = v;
      }
    }
    __syncthreads();
#pragma unroll
    for (int ks = 0; ks < 4; ++ks) {
      const int bcol = ks*64 + lq*16;
      const bf16x8 a0 = ld_frag(Wts, w*16 + lr, bcol);
#pragma unroll
      for (int mb = 0; mb < 8; ++mb) {
        const bf16x8 bm = ld_frag(Hs, mb*16 + lr, bcol);
        yacc[mb] = __builtin_amdgcn_mfma_f32_16x16x32_bf16(a0, bm, yacc[mb], 0, 0, 0);
      }
    }
  }
  // epilogue: Y{rank}[token][o] bf16
  {
    const int ob = w*16 + lq*4;
    const float4 b2 = *(const float4*)&seb2[ob];
#pragma unroll
    for (int mb = 0; mb < 8; ++mb) {
      const int tl = mb*16 + lr;
      if (tl < nt) {
        const int pk = stok[tl];
        const int tk = pk & 0x3FFFFFFF;
        const float wgt = swgt[tl];
        unsigned short* Yp = ((pk >> 30) ? Y1b : Y0b) + (long)tk*128 + ob;
        uint2 p;
        p.x = f2bf((yacc[mb][0] + b2.x) * wgt)
            | (f2bf((yacc[mb][1] + b2.y) * wgt) << 16);
        p.y = f2bf((yacc[mb][2] + b2.z) * wgt)
            | (f2bf((yacc[mb][3] + b2.w) * wgt) << 16);
        *(uint2*)Yp = p;
      }
    }
  }
}

// ---------------- fused mh + sc GEMM + fast-tanh + fixed-max softmax -------
__global__ __launch_bounds__(512)
void k_gemm2f(const unsigned short* __restrict__ Y0b,
              const unsigned short* __restrict__ Y1b,
              const unsigned short* __restrict__ wcb,
              const unsigned short* __restrict__ encb,
              const float* __restrict__ mask,
              const char* __restrict__ mflag,
              float* __restrict__ out) {
  const int bid = blockIdx.x;
  const int b = bid & 31, rt = bid >> 5;
  __shared__ unsigned short Amh[64*128];   // 16 KB: X then mh
  __shared__ unsigned short Bch[512*32];   // 32 KB: Wc then enc chunks
  __shared__ float red[64][9];
  __shared__ char sfl[64];
  const int tid = threadIdx.x;
  const int w = tid >> 6, l = tid & 63, lq = l >> 4, lr = l & 15;
  const long rowbase = (long)b*512 + rt*64;
#pragma unroll
  for (int s = 0; s < 2; ++s) {
    const int id = tid + s*512;           // 0..1023
    const int r = id >> 4, c16 = id & 15;
    const long yb = (rowbase + r)*128 + c16*8;
    const uint4 a = *(const uint4*)(Y0b + yb);
    const uint4 c = *(const uint4*)(Y1b + yb);
    uint4 p;
    p.x = f2bf(bflo(a.x)+bflo(c.x)) | (f2bf(bfhi(a.x)+bfhi(c.x)) << 16);
    p.y = f2bf(bflo(a.y)+bflo(c.y)) | (f2bf(bfhi(a.y)+bfhi(c.y)) << 16);
    p.z = f2bf(bflo(a.z)+bflo(c.z)) | (f2bf(bfhi(a.z)+bfhi(c.z)) << 16);
    p.w = f2bf(bflo(a.w)+bflo(c.w)) | (f2bf(bfhi(a.w)+bfhi(c.w)) << 16);
    *(uint4*)((char*)Amh + r*256 + ((c16*16) ^ ((r & 7) << 4))) = p;
  }
#pragma unroll
  for (int s = 0; s < 4; ++s) {
    const int id = tid + s*512;           // 0..2047
    const int fr = id >> 4, c16 = id & 15;
    const uint4 v = *(const uint4*)(wcb + (long)fr*128 + c16*8);
    *(uint4*)((char*)Bch + fr*256 + ((c16*16) ^ ((fr & 7) << 4))) = v;
  }
  if (tid < 64) sfl[tid] = mflag[rowbase + tid];
  __syncthreads();
  // Phase A: mh GEMM, 8 waves x 16 o-rows, D[o][m]
  {
    f32x4 macc[4];
#pragma unroll
    for (int m = 0; m < 4; ++m) macc[m] = (f32x4){0.f, 0.f, 0.f, 0.f};
#pragma unroll
    for (int ks = 0; ks < 4; ++ks) {
      const int bcol = ks*64 + lq*16;
      const bf16x8 a0 = ld_frag(Bch, w*16 + lr, bcol);
      const bf16x8 b0 = ld_frag(Amh, 0*16 + lr, bcol);
      const bf16x8 b1 = ld_frag(Amh, 1*16 + lr, bcol);
      const bf16x8 b2 = ld_frag(Amh, 2*16 + lr, bcol);
      const bf16x8 b3 = ld_frag(Amh, 3*16 + lr, bcol);
      macc[0] = __builtin_amdgcn_mfma_f32_16x16x32_bf16(a0, b0, macc[0], 0, 0, 0);
      macc[1] = __builtin_amdgcn_mfma_f32_16x16x32_bf16(a0, b1, macc[1], 0, 0, 0);
      macc[2] = __builtin_amdgcn_mfma_f32_16x16x32_bf16(a0, b2, macc[2], 0, 0, 0);
      macc[3] = __builtin_amdgcn_mfma_f32_16x16x32_bf16(a0, b3, macc[3], 0, 0, 0);
    }
    __syncthreads();
    const int o0 = w*16 + lq*4;
#pragma unroll
    for (int mb = 0; mb < 4; ++mb) {
      const int m = mb*16 + lr;
      uint2 p;
      p.x = f2bf(macc[mb][0]) | (f2bf(macc[mb][1]) << 16);
      p.y = f2bf(macc[mb][2]) | (f2bf(macc[mb][3]) << 16);
      *(uint2*)((char*)Amh + m*256 + ((o0*2) ^ ((m & 7) << 4))) = p;
    }
  }
  // Phase B: sc GEMM over enc + fused epilogue
  f32x4 acc[4][4];
#pragma unroll
  for (int mi = 0; mi < 4; ++mi)
#pragma unroll
    for (int ni = 0; ni < 4; ++ni) acc[mi][ni] = (f32x4){0.f, 0.f, 0.f, 0.f};
  for (int kc = 0; kc < 4; ++kc) {
    __syncthreads();
#pragma unroll
    for (int s = 0; s < 4; ++s) {
      const int id = tid + s*512;
      const int n = id >> 2, sl = id & 3;
      const uint4 v = *(const uint4*)(encb + ((long)b*512 + n)*128 + kc*32 + sl*8);
      *(uint4*)((char*)Bch + n*64 + ((sl*16) ^ ((n & 3) << 4))) = v;
    }
    __syncthreads();
    bf16x8 af[4], bfr[4];
#pragma unroll
    for (int mi = 0; mi < 4; ++mi) {
      const int r = mi*16 + lr;
      af[mi] = *(const bf16x8*)((const char*)Amh + r*256 + ((kc*64 + lq*16) ^ ((r & 7) << 4)));
    }
#pragma unroll
    for (int ni = 0; ni < 4; ++ni) {
      const int n = w*64 + ni*16 + lr;
      bfr[ni] = *(const bf16x8*)((const char*)Bch + n*64 + ((lq*16) ^ ((n & 3) << 4)));
    }
#pragma unroll
    for (int mi = 0; mi < 4; ++mi)
#pragma unroll
      for (int ni = 0; ni < 4; ++ni)
        acc[mi][ni] = __builtin_amdgcn_mfma_f32_16x16x32_bf16(af[mi], bfr[ni], acc[mi][ni], 0, 0, 0);
  }
  const float ISC = 1.f/11.313708498984761f;
  float rsum[4][4];
#pragma unroll
  for (int mi = 0; mi < 4; ++mi)
#pragma unroll
    for (int j = 0; j < 4; ++j) rsum[mi][j] = 0.f;
#pragma unroll
  for (int mi = 0; mi < 4; ++mi) {
#pragma unroll
    for (int j = 0; j < 4; ++j) {
      const int rl = mi*16 + lq*4 + j;
      const bool um = sfl[rl] != 0;
      const float* mrow = mask + (rowbase + rl)*512 + w*64 + lr;
#pragma unroll
      for (int ni = 0; ni < 4; ++ni) {
        const float sc = acc[mi][ni][j] * ISC;
        // fast exact tanh: sign(sc) * (1-t)/(1+t), t = exp(-2|sc|)
        const float t = __expf(-2.f * fabsf(sc));
        const float th = (1.f - t) * __builtin_amdgcn_rcpf(1.f + t);
        const float mv = um ? mrow[ni*16] : 0.f;
        const float li = copysignf(th, sc)*10.f + mv;
        const float e = __expf(li - 10.f);
        acc[mi][ni][j] = e;
        rsum[mi][j] += e;
      }
    }
  }
#pragma unroll
  for (int mi = 0; mi < 4; ++mi)
#pragma unroll
    for (int j = 0; j < 4; ++j) {
#pragma unroll
      for (int o = 1; o < 16; o <<= 1) rsum[mi][j] += __shfl_xor(rsum[mi][j], o);
    }
  if (lr == 0) {
#pragma unroll
    for (int mi = 0; mi < 4; ++mi)
#pragma unroll
      for (int j = 0; j < 4; ++j) red[mi*16 + lq*4 + j][w] = rsum[mi][j];
  }
  __syncthreads();
  if (tid < 64) {
    float s = 0.f;
#pragma unroll
    for (int wv = 0; wv < 8; ++wv) s += red[tid][wv];
    red[tid][8] = 1.f / s;
  }
  __syncthreads();
#pragma unroll
  for (int mi = 0; mi < 4; ++mi) {
#pragma unroll
    for (int j = 0; j < 4; ++j) {
      const int rl = mi*16 + lq*4 + j;
      const float inv = red[rl][8];
      float* orow = out + (rowbase + rl)*512 + w*64 + lr;
#pragma unroll
      for (int ni = 0; ni < 4; ++ni) orow[ni*16] = acc[mi][ni][j] * inv;
    }
  }
}

// ---------------------------------------------------------------------------
extern "C" void kernel_launch(void* const* d_in, const int* in_sizes, int n_in,
                              void* d_out, int out_size, void* d_ws, size_t ws_size,
                              hipStream_t stream) {
  (void)in_sizes; (void)n_in; (void)out_size; (void)ws_size;
  const float* pref  = (const float*)d_in[0];
  const float* graph = (const float*)d_in[1];
  const float* cap   = (const float*)d_in[2];
  const float* enc   = (const float*)d_in[3];
  const float* mask  = (const float*)d_in[4];
  const float* fc1w  = (const float*)d_in[5];
  const float* fc1b  = (const float*)d_in[6];
  const float* fc2w  = (const float*)d_in[7];
  const float* fc2b  = (const float*)d_in[8];
  const float* fc3w  = (const float*)d_in[9];
  const float* fc3b  = (const float*)d_in[10];
  const float* hWq   = (const float*)d_in[11];
  const float* hWk   = (const float*)d_in[12];
  const float* hWv   = (const float*)d_in[13];
  const float* hWc   = (const float*)d_in[14];
  const float* gw    = (const float*)d_in[15];
  const float* gpw   = (const float*)d_in[16];
  const float* ew1   = (const float*)d_in[17];
  const float* eb1   = (const float*)d_in[18];
  const float* ew2   = (const float*)d_in[19];
  const float* eb2   = (const float*)d_in[20];
  float* ws  = (float*)d_ws;
  float* out = (float*)d_out;
  unsigned short* Kbuf = (unsigned short*)out;
  unsigned short* Vtg  = (unsigned short*)(out + 1048576);
  unsigned short* ew1b = (unsigned short*)(out + 4194304);
  unsigned short* ew2b = (unsigned short*)(out + 4456448);
  unsigned short* AOb  = (unsigned short*)(ws + OFF_AO);
  unsigned short* Y0b  = (unsigned short*)(ws + OFF_Y0);
  unsigned short* Y1b  = (unsigned short*)(ws + OFF_Y1);
  unsigned short* encb = (unsigned short*)(ws + OFF_ENCB);
  unsigned short* wkb  = (unsigned short*)(ws + OFF_WKB);
  unsigned short* wvb  = (unsigned short*)(ws + OFF_WVB);
  unsigned short* wcb  = (unsigned short*)(ws + OFF_WCB);
  const char* mflag = (const char*)(ws + OFF_MFLAG);

  k_prep1<<<5121, 256, 0, stream>>>(pref, fc1w, fc1b, fc2w, fc2b, fc3w, fc3b,
                                    gpw, hWq, mask, ew1, ew2, enc,
                                    ew1b, ew2b, encb, ws);
  k_prep2<<<208, 256, 0, stream>>>(graph, hWq, hWk, hWv, hWc, ws);
  k_kv<<<dim3(256, 2), 256, 0, stream>>>(encb, wkb, wvb, Kbuf, Vtg);
  k_attn<<<1024, 512, 0, stream>>>(Kbuf, Vtg, ws, cap, mask, AOb);
  k_gate<<<64, 256, 0, stream>>>(AOb, gw, ws);
  k_moe<<<dim3(128, 8), 512, 0, stream>>>(AOb, ew1b, ew2b, eb1, eb2, ws, Y0b, Y1b);
  k_gemm2f<<<256, 512, 0, stream>>>(Y0b, Y1b, wcb, encb, mask, mflag, out);
}

// Round 15
// 110.213 us; speedup vs baseline: 1.1515x; 1.1515x over previous
//
#include <hip/hip_runtime.h>

// ---------------------------------------------------------------------------
// KP_Decoder: hypernet -> (k,v,q) -> attention -> top2 MoE -> combine softmax
// B=32 G=512 N=512 EMB=128 H=8 DK=16 E=8 FH=512 K=2
// R3-R13: bf16 MFMA everywhere; fused fixed-max softmaxes; q-split attn;
//         mask-flag skip; split prep; V pre-transposed; bf16 AO/Y; mh fused.
// R14: fast tanh kept (won ~6us). 128-token moe REVERTED (1 block/CU killed
//      inter-block overlap: +21us). R15 = R13 moe + R14 gemm2f.
// ---------------------------------------------------------------------------

typedef __attribute__((ext_vector_type(8))) __bf16 bf16x8;
typedef __attribute__((ext_vector_type(4))) float f32x4;

// ws layout (float offsets)
static constexpr long OFF_MID   = 0;        // 8
static constexpr long OFF_PREFL = 8;        // 8
static constexpr long OFF_WL    = 16;       // 128 (Wq[:,128] capacity col)
static constexpr long OFF_WKB   = 256;      // 128x128 bf16
static constexpr long OFF_WVB   = 8448;     // 128x128 bf16
static constexpr long OFF_WCB   = 16640;    // 128x128 bf16
static constexpr long OFF_QB    = 24832;    // 32x128 qbase fp32
static constexpr long OFF_MFLAG = 28928;    // 16384 bytes (4096 floats)
static constexpr long OFF_CNT   = 33024;    // 8 ints
static constexpr long OFF_TOK   = 33032;    // 8*16384 ints
static constexpr long OFF_WGT   = 164104;   // 8*16384 floats
static constexpr long OFF_AO    = 295176;   // 16384x128 bf16 AO (1,048,576 f)
static constexpr long OFF_Y0    = 1343752;  // 16384x128 bf16 Y0
static constexpr long OFF_Y1    = 2392328;  // 16384x128 bf16 Y1
static constexpr long OFF_ENCB  = 3440904;  // 16384x128 bf16 enc
// total 4,489,480 floats = 17.96 MB

__device__ __forceinline__ unsigned f2bf(float x) {
  union { float f; unsigned u; } v; v.f = x;
  return ((v.u + 0x7FFFu + ((v.u >> 16) & 1u)) >> 16) & 0xFFFFu;
}
__device__ __forceinline__ float bflo(unsigned u) {
  union { unsigned u; float f; } v; v.u = u << 16; return v.f;
}
__device__ __forceinline__ float bfhi(unsigned u) {
  union { unsigned u; float f; } v; v.u = u & 0xFFFF0000u; return v.f;
}

// ---------------- k_prep1: hypernet (1 block) + cvt + mask flags -----------
__global__ __launch_bounds__(256)
void k_prep1(const float* __restrict__ pref, const float* __restrict__ fc1w,
             const float* __restrict__ fc1b, const float* __restrict__ fc2w,
             const float* __restrict__ fc2b, const float* __restrict__ fc3w,
             const float* __restrict__ fc3b, const float* __restrict__ gpw,
             const float* __restrict__ hWq, const float* __restrict__ mask,
             const float* __restrict__ ew1, const float* __restrict__ ew2,
             const float* __restrict__ enc,
             unsigned short* __restrict__ w1b, unsigned short* __restrict__ w2b,
             unsigned short* __restrict__ encb, float* __restrict__ ws) {
  const int bid = blockIdx.x;
  const int tid = threadIdx.x;
  if (bid == 0) {
    __shared__ float h1[256];
    __shared__ float h2[256];
    __shared__ float mid[8];
    const float p0 = pref[0], p1 = pref[1];
    h1[tid] = fc1w[2*tid]*p0 + fc1w[2*tid+1]*p1 + fc1b[tid];
    __syncthreads();
    float s = 0.f;
    for (int j = 0; j < 256; ++j) s = fmaf(fc2w[tid*256+j], h1[j], s);
    h2[tid] = s + fc2b[tid];
    __syncthreads();
    if (tid < 8) {
      float s2 = 0.f;
      for (int j = 0; j < 256; ++j) s2 = fmaf(fc3w[tid*256+j], h2[j], s2);
      mid[tid] = s2 + fc3b[tid];
    }
    __syncthreads();
    if (tid < 8) {
      ws[OFF_MID + tid] = mid[tid];
      float s3 = 0.f;
      for (int i = 0; i < 8; ++i) s3 = fmaf(mid[i], gpw[i*8 + tid], s3);
      ws[OFF_PREFL + tid] = s3;
      ((int*)(ws + OFF_CNT))[tid] = 0;
    }
    if (tid >= 16 && tid < 144) {
      const int o = tid - 16;
      ws[OFF_WL + o] = hWq[((long)o*129 + 128)*2]*mid[0]
                     + hWq[((long)o*129 + 128)*2 + 1]*mid[1];
    }
    return;
  }
  if (bid <= 3072) {
    const int i = (bid-1)*256 + tid;
    const float* src;
    unsigned short* dst;
    if (i < 131072)      { src = ew1 + (long)i*4;          dst = w1b + (long)i*4; }
    else if (i < 262144) { src = ew2 + (long)(i-131072)*4; dst = w2b + (long)(i-131072)*4; }
    else                 { src = enc + (long)(i-262144)*4; dst = encb + (long)(i-262144)*4; }
    const float4 v = *(const float4*)src;
    uint2 p;
    p.x = f2bf(v.x) | (f2bf(v.y) << 16);
    p.y = f2bf(v.z) | (f2bf(v.w) << 16);
    *(uint2*)dst = p;
    return;
  }
  // mask flags: 8 rows per block
  __shared__ int fl[8];
  const int rowbase = (bid - 3073) * 8;
  const int r = tid >> 5, seg = tid & 31;
  if (tid < 8) fl[tid] = 0;
  __syncthreads();
  const float* mrow = mask + (long)(rowbase + r)*512 + seg*16;
  int nz = 0;
#pragma unroll
  for (int c = 0; c < 4; ++c) {
    const float4 v = *(const float4*)(mrow + c*4);
    nz |= (v.x != 0.f) | (v.y != 0.f) | (v.z != 0.f) | (v.w != 0.f);
  }
  if (nz) atomicOr(&fl[r], 1);
  __syncthreads();
  if (tid < 8) ((char*)(ws + OFF_MFLAG))[rowbase + tid] = (char)fl[tid];
}

// ---------------- k_prep2: Wk/Wv/Wc heads + qbase (reads mid from ws) ------
__global__ __launch_bounds__(256)
void k_prep2(const float* __restrict__ graph,
             const float* __restrict__ hWq, const float* __restrict__ hWk,
             const float* __restrict__ hWv, const float* __restrict__ hWc,
             float* __restrict__ ws) {
  const int bid = blockIdx.x;
  const int tid = threadIdx.x;
  __shared__ float mid[8];
  __shared__ float g[2][128];
  if (tid < 8) mid[tid] = ws[OFF_MID + tid];
  __syncthreads();
  if (bid < 192) {
    const int i = bid*256 + tid;   // 0..49151
    if (i < 16384) {
      ((unsigned short*)(ws + OFF_WKB))[i] =
          (unsigned short)f2bf(hWk[2*i]*mid[2] + hWk[2*i+1]*mid[3]);
    } else if (i < 32768) {
      const int j = i - 16384;
      ((unsigned short*)(ws + OFF_WVB))[j] =
          (unsigned short)f2bf(hWv[2*j]*mid[4] + hWv[2*j+1]*mid[5]);
    } else {
      const int j = i - 32768;
      ((unsigned short*)(ws + OFF_WCB))[j] =
          (unsigned short)f2bf(hWc[2*j]*mid[6] + hWc[2*j+1]*mid[7]);
    }
    return;
  }
  const int qb = bid - 192;
  const int b0 = qb*2;
  {
    const int bb = tid >> 7, ii = tid & 127;
    g[bb][ii] = graph[(b0+bb)*128 + ii];
  }
  __syncthreads();
  const float m0 = mid[0], m1 = mid[1];
  const int bb = tid >> 7, o = tid & 127;
  const float* hq = hWq + (long)o*129*2;
  float acc = 0.f;
  for (int i2 = 0; i2 < 128; ++i2) {
    const float w = hq[2*i2]*m0 + hq[2*i2+1]*m1;
    acc = fmaf(g[bb][i2], w, acc);
  }
  ws[OFF_QB + (b0+bb)*128 + o] = acc;
}

// ---------------- shared swizzled-LDS fragment loader (256B rows) ----------
__device__ __forceinline__ bf16x8 ld_frag(const unsigned short* base, int row, int bytecol) {
  const int addr = row*256 + (bytecol ^ ((row & 7) << 4));
  return *(const bf16x8*)((const char*)base + addr);
}

// ---------------- k_kv: bf16 MFMA GEMM, K row-major, V TRANSPOSED ----------
__global__ __launch_bounds__(256)
void k_kv(const unsigned short* __restrict__ encb,
          const unsigned short* __restrict__ wkb,
          const unsigned short* __restrict__ wvb,
          unsigned short* __restrict__ Kb, unsigned short* __restrict__ Vtg) {
  __shared__ unsigned short Ws[128*128];
  __shared__ unsigned short Xs[64*128];
  const int tid = threadIdx.x;
  const int nbase = blockIdx.x * 64;
  const unsigned short* Wb = blockIdx.y ? wvb : wkb;
#pragma unroll
  for (int s = 0; s < 8; ++s) {
    const int id = tid + s*256;
    const int fr = id >> 4, c16 = id & 15;
    const uint4 v = *(const uint4*)(Wb + (long)fr*128 + c16*8);
    *(uint4*)((char*)Ws + fr*256 + ((c16*16) ^ ((fr & 7) << 4))) = v;
  }
#pragma unroll
  for (int s = 0; s < 4; ++s) {
    const int id = tid + s*256;
    const int r = id >> 4, c16 = id & 15;
    const uint4 v = *(const uint4*)(encb + (long)(nbase + r)*128 + c16*8);
    *(uint4*)((char*)Xs + r*256 + ((c16*16) ^ ((r & 7) << 4))) = v;
  }
  __syncthreads();
  const int w = tid >> 6, l = tid & 63, lq = l >> 4, lr = l & 15;
  f32x4 acc[2][4];
#pragma unroll
  for (int a = 0; a < 2; ++a)
#pragma unroll
    for (int m = 0; m < 4; ++m) acc[a][m] = (f32x4){0.f, 0.f, 0.f, 0.f};
#pragma unroll
  for (int ks = 0; ks < 4; ++ks) {
    const int bcol = ks*64 + lq*16;
    const bf16x8 a0 = ld_frag(Ws, (2*w  )*16 + lr, bcol);
    const bf16x8 a1 = ld_frag(Ws, (2*w+1)*16 + lr, bcol);
    const bf16x8 b0 = ld_frag(Xs, 0*16 + lr, bcol);
    const bf16x8 b1 = ld_frag(Xs, 1*16 + lr, bcol);
    const bf16x8 b2 = ld_frag(Xs, 2*16 + lr, bcol);
    const bf16x8 b3 = ld_frag(Xs, 3*16 + lr, bcol);
    acc[0][0] = __builtin_amdgcn_mfma_f32_16x16x32_bf16(a0, b0, acc[0][0], 0, 0, 0);
    acc[0][1] = __builtin_amdgcn_mfma_f32_16x16x32_bf16(a0, b1, acc[0][1], 0, 0, 0);
    acc[0][2] = __builtin_amdgcn_mfma_f32_16x16x32_bf16(a0, b2, acc[0][2], 0, 0, 0);
    acc[0][3] = __builtin_amdgcn_mfma_f32_16x16x32_bf16(a0, b3, acc[0][3], 0, 0, 0);
    acc[1][0] = __builtin_amdgcn_mfma_f32_16x16x32_bf16(a1, b0, acc[1][0], 0, 0, 0);
    acc[1][1] = __builtin_amdgcn_mfma_f32_16x16x32_bf16(a1, b1, acc[1][1], 0, 0, 0);
    acc[1][2] = __builtin_amdgcn_mfma_f32_16x16x32_bf16(a1, b2, acc[1][2], 0, 0, 0);
    acc[1][3] = __builtin_amdgcn_mfma_f32_16x16x32_bf16(a1, b3, acc[1][3], 0, 0, 0);
  }
  if (blockIdx.y == 0) {
#pragma unroll
    for (int obi = 0; obi < 2; ++obi) {
      const int o0 = (2*w + obi)*16 + lq*4;
#pragma unroll
      for (int mb = 0; mb < 4; ++mb) {
        const long n = nbase + mb*16 + lr;
        uint2 pp;
        pp.x = f2bf(acc[obi][mb][0]) | (f2bf(acc[obi][mb][1]) << 16);
        pp.y = f2bf(acc[obi][mb][2]) | (f2bf(acc[obi][mb][3]) << 16);
        *(uint2*)(Kb + n*128 + o0) = pp;
      }
    }
  } else {
    const int b = nbase >> 9;
    const int nn0 = nbase & 511;
#pragma unroll
    for (int obi = 0; obi < 2; ++obi) {
      const int o0 = (2*w + obi)*16 + lq*4;
#pragma unroll
      for (int mb = 0; mb < 4; ++mb) {
        const int nn = nn0 + mb*16 + lr;
#pragma unroll
        for (int j = 0; j < 4; ++j) {
          const int o = o0 + j;
          Vtg[(((long)b*8 + (o >> 4))*16 + (o & 15))*512 + nn] =
              (unsigned short)f2bf(acc[obi][mb][j]);
        }
      }
    }
  }
}

// ---------------- MFMA flash attention v7: dual PV accumulators ------------
__global__ __launch_bounds__(512, 8)
void k_attn(const unsigned short* __restrict__ Kb,
            const unsigned short* __restrict__ Vtg,
            const float* __restrict__ ws, const float* __restrict__ cap,
            const float* __restrict__ mask, unsigned short* __restrict__ AOb) {
  const int bid = blockIdx.x;
  const int b = bid & 31, h = (bid >> 5) & 7, qh = bid >> 8;
  __shared__ unsigned short Kbf[512*24];  // 24 KB
  __shared__ unsigned short Vt[16*536];   // 16.75 KB
  __shared__ unsigned short Ps[8*16*40];  // 10 KB
  const int tid = threadIdx.x;
#pragma unroll
  for (int it = 0; it < 2; ++it) {
    const int i = tid + it*512;           // 0..1023
    const int n = i >> 1, hf = i & 1;
    const uint4 kv = *(const uint4*)(Kb + (long)(b*512 + n)*128 + h*16 + hf*8);
    *(uint4*)(Kbf + n*24 + hf*8) = kv;
    const int d = i >> 6, c = i & 63;
    const uint4 vv = *(const uint4*)(Vtg + ((long)(b*8 + h)*16 + d)*512 + c*8);
    *(uint4*)(Vt + d*536 + c*8) = vv;
  }
  const int w = tid >> 6, l = tid & 63;
  const int lq = l >> 4, lr = l & 15;
  const int grow = qh*128 + w*16 + lr;
  bf16x8 qf;
  {
    union { uint4 u; bf16x8 v; } cv;
    cv.u = make_uint4(0u, 0u, 0u, 0u);
    if (lq < 2) {
      const float* qbp = ws + OFF_QB + b*128 + h*16 + lq*8;
      const float* wlp = ws + OFF_WL + h*16 + lq*8;
      const float cp = cap[b*512 + grow];
      float qv[8];
#pragma unroll
      for (int j = 0; j < 8; ++j) qv[j] = (qbp[j] + cp*wlp[j]) * 0.25f;
      cv.u.x = f2bf(qv[0]) | (f2bf(qv[1]) << 16);
      cv.u.y = f2bf(qv[2]) | (f2bf(qv[3]) << 16);
      cv.u.z = f2bf(qv[4]) | (f2bf(qv[5]) << 16);
      cv.u.w = f2bf(qv[6]) | (f2bf(qv[7]) << 16);
    }
    qf = cv.v;
  }
  const int mf = ((const char*)(ws + OFF_MFLAG))[b*512 + grow];
  const bool usemask = __any(mf != 0);
  unsigned short* Pw = Ps + w*16*40;
  const int psw = (lr & 3) << 3;
  __syncthreads();
  float lsum = 0.f;
  f32x4 oaccA = {0.f, 0.f, 0.f, 0.f};
  f32x4 oaccB = {0.f, 0.f, 0.f, 0.f};
  const float* mrow = mask + ((long)(b*512 + grow))*512 + lq*4;
#pragma unroll 2
  for (int qc = 0; qc < 16; ++qc) {       // 16 chunks of 32 n, independent
    const int n0 = qc*32;
    f32x4 s[2];
#pragma unroll
    for (int nb = 0; nb < 2; ++nb) {
      bf16x8 kf;
      {
        union { uint4 u; bf16x8 v; } cv;
        cv.u = make_uint4(0u, 0u, 0u, 0u);
        if (lq < 2) cv.u = *(const uint4*)(Kbf + (n0 + nb*16 + lr)*24 + lq*8);
        kf = cv.v;
      }
      s[nb] = __builtin_amdgcn_mfma_f32_16x16x32_bf16(
          kf, qf, (f32x4){0.f, 0.f, 0.f, 0.f}, 0, 0, 0);
      if (usemask) {
        const float4 mk = *(const float4*)(mrow + n0 + nb*16);
        s[nb][0] += mk.x; s[nb][1] += mk.y; s[nb][2] += mk.z; s[nb][3] += mk.w;
      }
    }
#pragma unroll
    for (int nb = 0; nb < 2; ++nb) {
      const float e0 = __expf(s[nb][0]);
      const float e1 = __expf(s[nb][1]);
      const float e2 = __expf(s[nb][2]);
      const float e3 = __expf(s[nb][3]);
      lsum += (e0 + e1) + (e2 + e3);
      uint2 pp;
      asm("v_cvt_pk_bf16_f32 %0, %1, %2" : "=v"(pp.x) : "v"(e0), "v"(e1));
      asm("v_cvt_pk_bf16_f32 %0, %1, %2" : "=v"(pp.y) : "v"(e2), "v"(e3));
      *(uint2*)(Pw + lr*40 + ((nb*16 + lq*4) ^ psw)) = pp;
    }
    const bf16x8 va = *(const bf16x8*)(Vt + lr*536 + n0 + lq*8);
    const bf16x8 pb = *(const bf16x8*)(Pw + lr*40 + (lq*8 ^ psw));
    if (qc & 1) oaccB = __builtin_amdgcn_mfma_f32_16x16x32_bf16(va, pb, oaccB, 0, 0, 0);
    else        oaccA = __builtin_amdgcn_mfma_f32_16x16x32_bf16(va, pb, oaccA, 0, 0, 0);
  }
  lsum += __shfl_xor(lsum, 16);
  lsum += __shfl_xor(lsum, 32);
  const float inv = 1.f / lsum;
  uint2 op;
  op.x = f2bf((oaccA[0]+oaccB[0])*inv) | (f2bf((oaccA[1]+oaccB[1])*inv) << 16);
  op.y = f2bf((oaccA[2]+oaccB[2])*inv) | (f2bf((oaccA[3]+oaccB[3])*inv) << 16);
  *(uint2*)(AOb + (long)(b*512 + grow)*128 + h*16 + lq*4) = op;
}

// ---------------- gating: top-2 + expert lists (bf16 AO) -------------------
__global__ __launch_bounds__(256)
void k_gate(const unsigned short* __restrict__ AOb, const float* __restrict__ gw,
            float* __restrict__ ws) {
  const int tid = threadIdx.x;
  const int t = blockIdx.x*256 + tid;
  const unsigned short* x = AOb + (long)t*128;
  float lg[8];
  {
    const float* pl = ws + OFF_PREFL;
#pragma unroll
    for (int e = 0; e < 8; ++e) lg[e] = pl[e];
  }
  for (int i = 0; i < 128; i += 8) {
    const uint4 xv = *(const uint4*)(x + i);
    float xf[8];
    xf[0] = bflo(xv.x); xf[1] = bfhi(xv.x);
    xf[2] = bflo(xv.y); xf[3] = bfhi(xv.y);
    xf[4] = bflo(xv.z); xf[5] = bfhi(xv.z);
    xf[6] = bflo(xv.w); xf[7] = bfhi(xv.w);
#pragma unroll
    for (int u = 0; u < 8; ++u) {
      const float xi = xf[u];
      const float4 ga = *(const float4*)(gw + (i+u)*8);
      const float4 gb = *(const float4*)(gw + (i+u)*8 + 4);
      lg[0] = fmaf(xi, ga.x, lg[0]); lg[1] = fmaf(xi, ga.y, lg[1]);
      lg[2] = fmaf(xi, ga.z, lg[2]); lg[3] = fmaf(xi, ga.w, lg[3]);
      lg[4] = fmaf(xi, gb.x, lg[4]); lg[5] = fmaf(xi, gb.y, lg[5]);
      lg[6] = fmaf(xi, gb.z, lg[6]); lg[7] = fmaf(xi, gb.w, lg[7]);
    }
  }
  int i0 = 0; float v0 = lg[0];
#pragma unroll
  for (int e = 1; e < 8; ++e) if (lg[e] > v0) { v0 = lg[e]; i0 = e; }
  int i1 = -1; float v1 = -1e30f;
#pragma unroll
  for (int e = 0; e < 8; ++e) if (e != i0 && lg[e] > v1) { v1 = lg[e]; i1 = e; }
  const float e1 = __expf(v1 - v0);
  const float w0 = 1.f / (1.f + e1);
  const float w1 = 1.f - w0;
  __shared__ int bcnt[8];
  __shared__ int gbase[8];
  if (tid < 8) bcnt[tid] = 0;
  __syncthreads();
  const int p0 = atomicAdd(&bcnt[i0], 1);
  const int p1 = atomicAdd(&bcnt[i1], 1);
  __syncthreads();
  if (tid < 8) {
    int* cnt = (int*)(ws + OFF_CNT);
    gbase[tid] = (bcnt[tid] > 0) ? atomicAdd(&cnt[tid], bcnt[tid]) : 0;
  }
  __syncthreads();
  int* tokp = (int*)(ws + OFF_TOK);
  float* wgtp = ws + OFF_WGT;
  const int s0 = gbase[i0] + p0;
  tokp[i0*16384 + s0] = t;             // rank 0
  wgtp[i0*16384 + s0] = w0;
  const int s1 = gbase[i1] + p1;
  tokp[i1*16384 + s1] = t | (1 << 30); // rank 1
  wgtp[i1*16384 + s1] = w1;
}

// ---------------- MoE experts: bf16 MFMA, 64-token tiles (R13 shape) -------
__global__ __launch_bounds__(256)
void k_moe(const unsigned short* __restrict__ AOb,
           const unsigned short* __restrict__ w1b,
           const unsigned short* __restrict__ w2b,
           const float* __restrict__ eb1, const float* __restrict__ eb2,
           float* __restrict__ ws,
           unsigned short* __restrict__ Y0b, unsigned short* __restrict__ Y1b) {
  const int e = blockIdx.y;
  const int ce = ((const int*)(ws + OFF_CNT))[e];
  const int base = blockIdx.x * 64;
  if (base >= ce) return;
  const int nt = min(64, ce - base);

  __shared__ unsigned short Xs[64*128];
  __shared__ unsigned short Wts[128*128];
  __shared__ unsigned short Hs[64*128];
  __shared__ float seb1[512];
  __shared__ float seb2[128];
  __shared__ int   stok[64];
  __shared__ float swgt[64];

  const int tid = threadIdx.x;
  if (tid < 64) {
    if (tid < nt) {
      stok[tid] = ((const int*)(ws + OFF_TOK))[e*16384 + base + tid];
      swgt[tid] = (ws + OFF_WGT)[e*16384 + base + tid];
    } else { stok[tid] = -1; swgt[tid] = 0.f; }
  }
  for (int i = tid; i < 512; i += 256) seb1[i] = eb1[e*512 + i];
  if (tid < 128) seb2[tid] = eb2[e*128 + tid];
  __syncthreads();

#pragma unroll
  for (int r4 = 0; r4 < 4; ++r4) {
    const int id = tid + r4*256;          // 0..1023
    const int r = id >> 4, c16 = id & 15;
    const int pk = stok[r];
    uint4 v = make_uint4(0u, 0u, 0u, 0u);
    if (pk >= 0) v = *(const uint4*)(AOb + (long)(pk & 0x3FFFFFFF)*128 + c16*8);
    *(uint4*)((char*)Xs + r*256 + ((c16*16) ^ ((r & 7) << 4))) = v;
  }

  const int w  = tid >> 6;
  const int l  = tid & 63;
  const int lq = l >> 4;
  const int lr = l & 15;

  f32x4 yacc[2][4];
#pragma unroll
  for (int a = 0; a < 2; ++a)
#pragma unroll
    for (int m = 0; m < 4; ++m) yacc[a][m] = (f32x4){0.f, 0.f, 0.f, 0.f};

  for (int fc = 0; fc < 4; ++fc) {
    __syncthreads();
    {
      const long wb = (long)(e*512 + fc*128) * 128;
#pragma unroll
      for (int s = 0; s < 8; ++s) {
        const int id = tid + s*256;
        const int fr = id >> 4, c16 = id & 15;
        const uint4 v = *(const uint4*)(w1b + wb + (long)fr*128 + c16*8);
        *(uint4*)((char*)Wts + fr*256 + ((c16*16) ^ ((fr & 7) << 4))) = v;
      }
    }
    __syncthreads();
    f32x4 hacc[2][4];
#pragma unroll
    for (int a = 0; a < 2; ++a)
#pragma unroll
      for (int m = 0; m < 4; ++m) hacc[a][m] = (f32x4){0.f, 0.f, 0.f, 0.f};
#pragma unroll
    for (int ks = 0; ks < 4; ++ks) {
      const int bcol = ks*64 + lq*16;
      const bf16x8 a0 = ld_frag(Wts, (2*w  )*16 + lr, bcol);
      const bf16x8 a1 = ld_frag(Wts, (2*w+1)*16 + lr, bcol);
      const bf16x8 b0 = ld_frag(Xs,  0*16 + lr, bcol);
      const bf16x8 b1 = ld_frag(Xs,  1*16 + lr, bcol);
      const bf16x8 b2 = ld_frag(Xs,  2*16 + lr, bcol);
      const bf16x8 b3 = ld_frag(Xs,  3*16 + lr, bcol);
      hacc[0][0] = __builtin_amdgcn_mfma_f32_16x16x32_bf16(a0, b0, hacc[0][0], 0, 0, 0);
      hacc[0][1] = __builtin_amdgcn_mfma_f32_16x16x32_bf16(a0, b1, hacc[0][1], 0, 0, 0);
      hacc[0][2] = __builtin_amdgcn_mfma_f32_16x16x32_bf16(a0, b2, hacc[0][2], 0, 0, 0);
      hacc[0][3] = __builtin_amdgcn_mfma_f32_16x16x32_bf16(a0, b3, hacc[0][3], 0, 0, 0);
      hacc[1][0] = __builtin_amdgcn_mfma_f32_16x16x32_bf16(a1, b0, hacc[1][0], 0, 0, 0);
      hacc[1][1] = __builtin_amdgcn_mfma_f32_16x16x32_bf16(a1, b1, hacc[1][1], 0, 0, 0);
      hacc[1][2] = __builtin_amdgcn_mfma_f32_16x16x32_bf16(a1, b2, hacc[1][2], 0, 0, 0);
      hacc[1][3] = __builtin_amdgcn_mfma_f32_16x16x32_bf16(a1, b3, hacc[1][3], 0, 0, 0);
    }
    __syncthreads();
#pragma unroll
    for (int fbi = 0; fbi < 2; ++fbi) {
      const int fb = (2*w + fbi)*16 + lq*4;
      const float4 bia = *(const float4*)&seb1[fc*128 + fb];
#pragma unroll
      for (int mb = 0; mb < 4; ++mb) {
        const int m = mb*16 + lr;
        const float h0 = fmaxf(hacc[fbi][mb][0] + bia.x, 0.f);
        const float h1 = fmaxf(hacc[fbi][mb][1] + bia.y, 0.f);
        const float h2 = fmaxf(hacc[fbi][mb][2] + bia.z, 0.f);
        const float h3 = fmaxf(hacc[fbi][mb][3] + bia.w, 0.f);
        uint2 p;
        p.x = f2bf(h0) | (f2bf(h1) << 16);
        p.y = f2bf(h2) | (f2bf(h3) << 16);
        const int bc = (fb*2) ^ ((m & 7) << 4);
        *(uint2*)((char*)Hs + m*256 + bc) = p;
      }
    }
    {
      const long wb = (long)(e*128) * 512 + fc*128;
#pragma unroll
      for (int s = 0; s < 8; ++s) {
        const int id = tid + s*256;
        const int orr = id >> 4, c16 = id & 15;
        const uint4 v = *(const uint4*)(w2b + wb + (long)orr*512 + c16*8);
        *(uint4*)((char*)Wts + orr*256 + ((c16*16) ^ ((orr & 7) << 4))) = v;
      }
    }
    __syncthreads();
#pragma unroll
    for (int ks = 0; ks < 4; ++ks) {
      const int bcol = ks*64 + lq*16;
      const bf16x8 a0 = ld_frag(Wts, (2*w  )*16 + lr, bcol);
      const bf16x8 a1 = ld_frag(Wts, (2*w+1)*16 + lr, bcol);
      const bf16x8 b0 = ld_frag(Hs,  0*16 + lr, bcol);
      const bf16x8 b1 = ld_frag(Hs,  1*16 + lr, bcol);
      const bf16x8 b2 = ld_frag(Hs,  2*16 + lr, bcol);
      const bf16x8 b3 = ld_frag(Hs,  3*16 + lr, bcol);
      yacc[0][0] = __builtin_amdgcn_mfma_f32_16x16x32_bf16(a0, b0, yacc[0][0], 0, 0, 0);
      yacc[0][1] = __builtin_amdgcn_mfma_f32_16x16x32_bf16(a0, b1, yacc[0][1], 0, 0, 0);
      yacc[0][2] = __builtin_amdgcn_mfma_f32_16x16x32_bf16(a0, b2, yacc[0][2], 0, 0, 0);
      yacc[0][3] = __builtin_amdgcn_mfma_f32_16x16x32_bf16(a0, b3, yacc[0][3], 0, 0, 0);
      yacc[1][0] = __builtin_amdgcn_mfma_f32_16x16x32_bf16(a1, b0, yacc[1][0], 0, 0, 0);
      yacc[1][1] = __builtin_amdgcn_mfma_f32_16x16x32_bf16(a1, b1, yacc[1][1], 0, 0, 0);
      yacc[1][2] = __builtin_amdgcn_mfma_f32_16x16x32_bf16(a1, b2, yacc[1][2], 0, 0, 0);
      yacc[1][3] = __builtin_amdgcn_mfma_f32_16x16x32_bf16(a1, b3, yacc[1][3], 0, 0, 0);
    }
  }
#pragma unroll
  for (int obi = 0; obi < 2; ++obi) {
    const int ob = (2*w + obi)*16 + lq*4;
    const float4 b2 = *(const float4*)&seb2[ob];
#pragma unroll
    for (int mb = 0; mb < 4; ++mb) {
      const int tl = mb*16 + lr;
      if (tl < nt) {
        const int pk = stok[tl];
        const int tk = pk & 0x3FFFFFFF;
        const float wgt = swgt[tl];
        unsigned short* Yp = ((pk >> 30) ? Y1b : Y0b) + (long)tk*128 + ob;
        uint2 p;
        p.x = f2bf((yacc[obi][mb][0] + b2.x) * wgt)
            | (f2bf((yacc[obi][mb][1] + b2.y) * wgt) << 16);
        p.y = f2bf((yacc[obi][mb][2] + b2.z) * wgt)
            | (f2bf((yacc[obi][mb][3] + b2.w) * wgt) << 16);
        *(uint2*)Yp = p;
      }
    }
  }
}

// ---------------- fused mh + sc GEMM + fast-tanh + fixed-max softmax -------
__global__ __launch_bounds__(512)
void k_gemm2f(const unsigned short* __restrict__ Y0b,
              const unsigned short* __restrict__ Y1b,
              const unsigned short* __restrict__ wcb,
              const unsigned short* __restrict__ encb,
              const float* __restrict__ mask,
              const char* __restrict__ mflag,
              float* __restrict__ out) {
  const int bid = blockIdx.x;
  const int b = bid & 31, rt = bid >> 5;
  __shared__ unsigned short Amh[64*128];   // 16 KB: X then mh
  __shared__ unsigned short Bch[512*32];   // 32 KB: Wc then enc chunks
  __shared__ float red[64][9];
  __shared__ char sfl[64];
  const int tid = threadIdx.x;
  const int w = tid >> 6, l = tid & 63, lq = l >> 4, lr = l & 15;
  const long rowbase = (long)b*512 + rt*64;
#pragma unroll
  for (int s = 0; s < 2; ++s) {
    const int id = tid + s*512;           // 0..1023
    const int r = id >> 4, c16 = id & 15;
    const long yb = (rowbase + r)*128 + c16*8;
    const uint4 a = *(const uint4*)(Y0b + yb);
    const uint4 c = *(const uint4*)(Y1b + yb);
    uint4 p;
    p.x = f2bf(bflo(a.x)+bflo(c.x)) | (f2bf(bfhi(a.x)+bfhi(c.x)) << 16);
    p.y = f2bf(bflo(a.y)+bflo(c.y)) | (f2bf(bfhi(a.y)+bfhi(c.y)) << 16);
    p.z = f2bf(bflo(a.z)+bflo(c.z)) | (f2bf(bfhi(a.z)+bfhi(c.z)) << 16);
    p.w = f2bf(bflo(a.w)+bflo(c.w)) | (f2bf(bfhi(a.w)+bfhi(c.w)) << 16);
    *(uint4*)((char*)Amh + r*256 + ((c16*16) ^ ((r & 7) << 4))) = p;
  }
#pragma unroll
  for (int s = 0; s < 4; ++s) {
    const int id = tid + s*512;           // 0..2047
    const int fr = id >> 4, c16 = id & 15;
    const uint4 v = *(const uint4*)(wcb + (long)fr*128 + c16*8);
    *(uint4*)((char*)Bch + fr*256 + ((c16*16) ^ ((fr & 7) << 4))) = v;
  }
  if (tid < 64) sfl[tid] = mflag[rowbase + tid];
  __syncthreads();
  // Phase A: mh GEMM, 8 waves x 16 o-rows, D[o][m]
  {
    f32x4 macc[4];
#pragma unroll
    for (int m = 0; m < 4; ++m) macc[m] = (f32x4){0.f, 0.f, 0.f, 0.f};
#pragma unroll
    for (int ks = 0; ks < 4; ++ks) {
      const int bcol = ks*64 + lq*16;
      const bf16x8 a0 = ld_frag(Bch, w*16 + lr, bcol);
      const bf16x8 b0 = ld_frag(Amh, 0*16 + lr, bcol);
      const bf16x8 b1 = ld_frag(Amh, 1*16 + lr, bcol);
      const bf16x8 b2 = ld_frag(Amh, 2*16 + lr, bcol);
      const bf16x8 b3 = ld_frag(Amh, 3*16 + lr, bcol);
      macc[0] = __builtin_amdgcn_mfma_f32_16x16x32_bf16(a0, b0, macc[0], 0, 0, 0);
      macc[1] = __builtin_amdgcn_mfma_f32_16x16x32_bf16(a0, b1, macc[1], 0, 0, 0);
      macc[2] = __builtin_amdgcn_mfma_f32_16x16x32_bf16(a0, b2, macc[2], 0, 0, 0);
      macc[3] = __builtin_amdgcn_mfma_f32_16x16x32_bf16(a0, b3, macc[3], 0, 0, 0);
    }
    __syncthreads();
    const int o0 = w*16 + lq*4;
#pragma unroll
    for (int mb = 0; mb < 4; ++mb) {
      const int m = mb*16 + lr;
      uint2 p;
      p.x = f2bf(macc[mb][0]) | (f2bf(macc[mb][1]) << 16);
      p.y = f2bf(macc[mb][2]) | (f2bf(macc[mb][3]) << 16);
      *(uint2*)((char*)Amh + m*256 + ((o0*2) ^ ((m & 7) << 4))) = p;
    }
  }
  // Phase B: sc GEMM over enc + fused epilogue
  f32x4 acc[4][4];
#pragma unroll
  for (int mi = 0; mi < 4; ++mi)
#pragma unroll
    for (int ni = 0; ni < 4; ++ni) acc[mi][ni] = (f32x4){0.f, 0.f, 0.f, 0.f};
  for (int kc = 0; kc < 4; ++kc) {
    __syncthreads();
#pragma unroll
    for (int s = 0; s < 4; ++s) {
      const int id = tid + s*512;
      const int n = id >> 2, sl = id & 3;
      const uint4 v = *(const uint4*)(encb + ((long)b*512 + n)*128 + kc*32 + sl*8);
      *(uint4*)((char*)Bch + n*64 + ((sl*16) ^ ((n & 3) << 4))) = v;
    }
    __syncthreads();
    bf16x8 af[4], bfr[4];
#pragma unroll
    for (int mi = 0; mi < 4; ++mi) {
      const int r = mi*16 + lr;
      af[mi] = *(const bf16x8*)((const char*)Amh + r*256 + ((kc*64 + lq*16) ^ ((r & 7) << 4)));
    }
#pragma unroll
    for (int ni = 0; ni < 4; ++ni) {
      const int n = w*64 + ni*16 + lr;
      bfr[ni] = *(const bf16x8*)((const char*)Bch + n*64 + ((lq*16) ^ ((n & 3) << 4)));
    }
#pragma unroll
    for (int mi = 0; mi < 4; ++mi)
#pragma unroll
      for (int ni = 0; ni < 4; ++ni)
        acc[mi][ni] = __builtin_amdgcn_mfma_f32_16x16x32_bf16(af[mi], bfr[ni], acc[mi][ni], 0, 0, 0);
  }
  const float ISC = 1.f/11.313708498984761f;
  float rsum[4][4];
#pragma unroll
  for (int mi = 0; mi < 4; ++mi)
#pragma unroll
    for (int j = 0; j < 4; ++j) rsum[mi][j] = 0.f;
#pragma unroll
  for (int mi = 0; mi < 4; ++mi) {
#pragma unroll
    for (int j = 0; j < 4; ++j) {
      const int rl = mi*16 + lq*4 + j;
      const bool um = sfl[rl] != 0;
      const float* mrow = mask + (rowbase + rl)*512 + w*64 + lr;
#pragma unroll
      for (int ni = 0; ni < 4; ++ni) {
        const float sc = acc[mi][ni][j] * ISC;
        // fast exact tanh: sign(sc) * (1-t)/(1+t), t = exp(-2|sc|)
        const float t = __expf(-2.f * fabsf(sc));
        const float th = (1.f - t) * __builtin_amdgcn_rcpf(1.f + t);
        const float mv = um ? mrow[ni*16] : 0.f;
        const float li = copysignf(th, sc)*10.f + mv;
        const float e = __expf(li - 10.f);
        acc[mi][ni][j] = e;
        rsum[mi][j] += e;
      }
    }
  }
#pragma unroll
  for (int mi = 0; mi < 4; ++mi)
#pragma unroll
    for (int j = 0; j < 4; ++j) {
#pragma unroll
      for (int o = 1; o < 16; o <<= 1) rsum[mi][j] += __shfl_xor(rsum[mi][j], o);
    }
  if (lr == 0) {
#pragma unroll
    for (int mi = 0; mi < 4; ++mi)
#pragma unroll
      for (int j = 0; j < 4; ++j) red[mi*16 + lq*4 + j][w] = rsum[mi][j];
  }
  __syncthreads();
  if (tid < 64) {
    float s = 0.f;
#pragma unroll
    for (int wv = 0; wv < 8; ++wv) s += red[tid][wv];
    red[tid][8] = 1.f / s;
  }
  __syncthreads();
#pragma unroll
  for (int mi = 0; mi < 4; ++mi) {
#pragma unroll
    for (int j = 0; j < 4; ++j) {
      const int rl = mi*16 + lq*4 + j;
      const float inv = red[rl][8];
      float* orow = out + (rowbase + rl)*512 + w*64 + lr;
#pragma unroll
      for (int ni = 0; ni < 4; ++ni) orow[ni*16] = acc[mi][ni][j] * inv;
    }
  }
}

// ---------------------------------------------------------------------------
extern "C" void kernel_launch(void* const* d_in, const int* in_sizes, int n_in,
                              void* d_out, int out_size, void* d_ws, size_t ws_size,
                              hipStream_t stream) {
  (void)in_sizes; (void)n_in; (void)out_size; (void)ws_size;
  const float* pref  = (const float*)d_in[0];
  const float* graph = (const float*)d_in[1];
  const float* cap   = (const float*)d_in[2];
  const float* enc   = (const float*)d_in[3];
  const float* mask  = (const float*)d_in[4];
  const float* fc1w  = (const float*)d_in[5];
  const float* fc1b  = (const float*)d_in[6];
  const float* fc2w  = (const float*)d_in[7];
  const float* fc2b  = (const float*)d_in[8];
  const float* fc3w  = (const float*)d_in[9];
  const float* fc3b  = (const float*)d_in[10];
  const float* hWq   = (const float*)d_in[11];
  const float* hWk   = (const float*)d_in[12];
  const float* hWv   = (const float*)d_in[13];
  const float* hWc   = (const float*)d_in[14];
  const float* gw    = (const float*)d_in[15];
  const float* gpw   = (const float*)d_in[16];
  const float* ew1   = (const float*)d_in[17];
  const float* eb1   = (const float*)d_in[18];
  const float* ew2   = (const float*)d_in[19];
  const float* eb2   = (const float*)d_in[20];
  float* ws  = (float*)d_ws;
  float* out = (float*)d_out;
  unsigned short* Kbuf = (unsigned short*)out;
  unsigned short* Vtg  = (unsigned short*)(out + 1048576);
  unsigned short* ew1b = (unsigned short*)(out + 4194304);
  unsigned short* ew2b = (unsigned short*)(out + 4456448);
  unsigned short* AOb  = (unsigned short*)(ws + OFF_AO);
  unsigned short* Y0b  = (unsigned short*)(ws + OFF_Y0);
  unsigned short* Y1b  = (unsigned short*)(ws + OFF_Y1);
  unsigned short* encb = (unsigned short*)(ws + OFF_ENCB);
  unsigned short* wkb  = (unsigned short*)(ws + OFF_WKB);
  unsigned short* wvb  = (unsigned short*)(ws + OFF_WVB);
  unsigned short* wcb  = (unsigned short*)(ws + OFF_WCB);
  const char* mflag = (const char*)(ws + OFF_MFLAG);

  k_prep1<<<5121, 256, 0, stream>>>(pref, fc1w, fc1b, fc2w, fc2b, fc3w, fc3b,
                                    gpw, hWq, mask, ew1, ew2, enc,
                                    ew1b, ew2b, encb, ws);
  k_prep2<<<208, 256, 0, stream>>>(graph, hWq, hWk, hWv, hWc, ws);
  k_kv<<<dim3(256, 2), 256, 0, stream>>>(encb, wkb, wvb, Kbuf, Vtg);
  k_attn<<<1024, 512, 0, stream>>>(Kbuf, Vtg, ws, cap, mask, AOb);
  k_gate<<<64, 256, 0, stream>>>(AOb, gw, ws);
  k_moe<<<dim3(256, 8), 256, 0, stream>>>(AOb, ew1b, ew2b, eb1, eb2, ws, Y0b, Y1b);
  k_gemm2f<<<256, 512, 0, stream>>>(Y0b, Y1b, wcb, encb, mask, mflag, out);
}